// Round 1
// baseline (594.966 us; speedup 1.0000x reference)
//
#include <hip/hip_runtime.h>
#include <math.h>

#define BB 8
#define CC 64
#define NA 4096   // H*W
#define KA 32     // C_a

#define RB 64     // rows per block (softmax rows n)
#define MT 64     // m-tile (softmax cols / PV reduction dim)

// ---------------- Kernel 1: g = W*x + b, per-pixel norms ----------------
__global__ __launch_bounds__(256) void k_g(const float* __restrict__ x,
                                           const float* __restrict__ W,
                                           const float* __restrict__ bias,
                                           float* __restrict__ g,
                                           float* __restrict__ norms) {
    __shared__ float Wl[KA * CC];
    __shared__ float bl[KA];
    int tid = threadIdx.x;
    for (int i = tid; i < KA * CC; i += 256) Wl[i] = W[i];
    if (tid < KA) bl[tid] = bias[tid];
    __syncthreads();

    int b = blockIdx.y;
    int n = blockIdx.x * 256 + tid;

    float acc[KA];
#pragma unroll
    for (int k = 0; k < KA; k++) acc[k] = 0.f;

    const float* xp = x + (size_t)b * CC * NA + n;
#pragma unroll 4
    for (int c = 0; c < CC; c++) {
        float xv = xp[(size_t)c * NA];
#pragma unroll
        for (int k = 0; k < KA; k++) acc[k] = fmaf(Wl[k * CC + c], xv, acc[k]);
    }

    float ss = 0.f;
    float* gp = g + (size_t)b * KA * NA + n;
#pragma unroll
    for (int k = 0; k < KA; k++) {
        float v = acc[k] + bl[k];
        gp[(size_t)k * NA] = v;
        ss = fmaf(v, v, ss);
    }
    norms[b * NA + n] = sqrtf(ss);
}

// ---------------- Kernel 1b: per-batch max norm ----------------
__global__ __launch_bounds__(256) void k_gmax(const float* __restrict__ norms,
                                              float* __restrict__ gmaxp) {
    int b = blockIdx.x, tid = threadIdx.x;
    float m = 0.f;
    for (int i = tid; i < NA; i += 256) m = fmaxf(m, norms[b * NA + i]);
#pragma unroll
    for (int off = 1; off < 64; off <<= 1) m = fmaxf(m, __shfl_xor(m, off));
    __shared__ float red[4];
    if ((tid & 63) == 0) red[tid >> 6] = m;
    __syncthreads();
    if (tid == 0) gmaxp[b] = fmaxf(fmaxf(red[0], red[1]), fmaxf(red[2], red[3]));
}

// ---------------- Kernel 2: fused scores -> softmax -> alpha + PV ----------------
// Block handles RB=64 rows of one batch. Two passes over all m:
//   pass 1: denominators sum_m exp(s - M_n)   (M_n = ||g_n||*gmax, safe bound)
//   pass 2: alpha = exp(s - M_n)/denom -> global write, PV accumulate.
__global__ __launch_bounds__(256) void k_attn(const float* __restrict__ x,
                                              const float* __restrict__ g,
                                              const float* __restrict__ norms,
                                              const float* __restrict__ gmaxp,
                                              float* __restrict__ out,
                                              float* __restrict__ alpha) {
    __shared__ __align__(16) float grows[KA][RB + 4];   // [k][r]
    __shared__ __align__(16) float gtile[KA][MT + 4];   // [k][m]
    __shared__ __align__(16) float atile[MT][RB + 4];   // [m][r]
    __shared__ __align__(16) float xtile[MT][CC + 4];   // [m][c]
    __shared__ float Mrow[RB];
    __shared__ float linv[RB];

    int tid = threadIdx.x;
    int b = blockIdx.y;
    int n0 = blockIdx.x * RB;
    int rq = tid >> 4;   // 0..15
    int mq = tid & 15;   // 0..15

    // load g rows for this block: g[b][k][n0 + r]
    {
        int k = tid >> 3;          // 0..31
        int r8 = (tid & 7) * 8;    // 0..56
        const float* gp = g + ((size_t)(b * KA + k)) * NA + n0 + r8;
        *(float4*)&grows[k][r8] = *(const float4*)gp;
        *(float4*)&grows[k][r8 + 4] = *(const float4*)(gp + 4);
    }
    if (tid < RB) Mrow[tid] = norms[b * NA + n0 + tid] * gmaxp[b];
    __syncthreads();

    float Mreg[4];
#pragma unroll
    for (int i = 0; i < 4; i++) Mreg[i] = Mrow[rq * 4 + i];

    // ---------------- pass 1: denominators ----------------
    float lsum[4] = {0.f, 0.f, 0.f, 0.f};
    for (int t = 0; t < NA / MT; t++) {
        {
            int k = tid >> 3;
            int m8 = (tid & 7) * 8;
            const float* gp = g + ((size_t)(b * KA + k)) * NA + t * MT + m8;
            *(float4*)&gtile[k][m8] = *(const float4*)gp;
            *(float4*)&gtile[k][m8 + 4] = *(const float4*)(gp + 4);
        }
        __syncthreads();

        float s[4][4];
#pragma unroll
        for (int i = 0; i < 4; i++)
#pragma unroll
            for (int j = 0; j < 4; j++) s[i][j] = 0.f;
#pragma unroll 8
        for (int k = 0; k < KA; k++) {
            float4 av = *(const float4*)&grows[k][rq * 4];
            float4 bv = *(const float4*)&gtile[k][mq * 4];
            float aa[4] = {av.x, av.y, av.z, av.w};
            float bb[4] = {bv.x, bv.y, bv.z, bv.w};
#pragma unroll
            for (int i = 0; i < 4; i++)
#pragma unroll
                for (int j = 0; j < 4; j++) s[i][j] = fmaf(aa[i], bb[j], s[i][j]);
        }
#pragma unroll
        for (int i = 0; i < 4; i++)
#pragma unroll
            for (int j = 0; j < 4; j++) lsum[i] += __expf(s[i][j] - Mreg[i]);
        __syncthreads();
    }
    // reduce over the 16 mq-lanes sharing each row group (lanes differ in bits 0..3)
#pragma unroll
    for (int i = 0; i < 4; i++) {
        float v = lsum[i];
        v += __shfl_xor(v, 1);
        v += __shfl_xor(v, 2);
        v += __shfl_xor(v, 4);
        v += __shfl_xor(v, 8);
        if (mq == 0) linv[rq * 4 + i] = 1.0f / v;
    }
    __syncthreads();
    float Lreg[4];
#pragma unroll
    for (int i = 0; i < 4; i++) Lreg[i] = linv[rq * 4 + i];

    // ---------------- pass 2: alpha write + PV ----------------
    float pv[4][4];
#pragma unroll
    for (int i = 0; i < 4; i++)
#pragma unroll
        for (int j = 0; j < 4; j++) pv[i][j] = 0.f;

    float* aptr = alpha + (size_t)b * NA * NA;

    for (int t = 0; t < NA / MT; t++) {
        {
            int k = tid >> 3;
            int m8 = (tid & 7) * 8;
            const float* gp = g + ((size_t)(b * KA + k)) * NA + t * MT + m8;
            *(float4*)&gtile[k][m8] = *(const float4*)gp;
            *(float4*)&gtile[k][m8 + 4] = *(const float4*)(gp + 4);
        }
        {
            // xtile[m][c] <- x[b][c][t*MT + m]  (transpose on the fly)
            int cb = tid >> 4;          // 0..15
            int m4 = (tid & 15) * 4;    // 0..60
#pragma unroll
            for (int ccb = 0; ccb < 4; ccb++) {
                int c = cb + ccb * 16;
                float4 v = *(const float4*)(x + ((size_t)(b * CC + c)) * NA + t * MT + m4);
                xtile[m4 + 0][c] = v.x;
                xtile[m4 + 1][c] = v.y;
                xtile[m4 + 2][c] = v.z;
                xtile[m4 + 3][c] = v.w;
            }
        }
        __syncthreads();

        float s[4][4];
#pragma unroll
        for (int i = 0; i < 4; i++)
#pragma unroll
            for (int j = 0; j < 4; j++) s[i][j] = 0.f;
#pragma unroll 8
        for (int k = 0; k < KA; k++) {
            float4 av = *(const float4*)&grows[k][rq * 4];
            float4 bv = *(const float4*)&gtile[k][mq * 4];
            float aa[4] = {av.x, av.y, av.z, av.w};
            float bb[4] = {bv.x, bv.y, bv.z, bv.w};
#pragma unroll
            for (int i = 0; i < 4; i++)
#pragma unroll
                for (int j = 0; j < 4; j++) s[i][j] = fmaf(aa[i], bb[j], s[i][j]);
        }

        float a[4][4];
#pragma unroll
        for (int i = 0; i < 4; i++)
#pragma unroll
            for (int j = 0; j < 4; j++) a[i][j] = __expf(s[i][j] - Mreg[i]) * Lreg[i];

        // global alpha write: row n0+rq*4+i, cols t*MT + mq*4 .. +3
#pragma unroll
        for (int i = 0; i < 4; i++) {
            float4 v = make_float4(a[i][0], a[i][1], a[i][2], a[i][3]);
            *(float4*)(aptr + (size_t)(n0 + rq * 4 + i) * NA + t * MT + mq * 4) = v;
        }
        // atile[m][r] (transposed for PV), float4 over rows
#pragma unroll
        for (int j = 0; j < 4; j++) {
            float4 v = make_float4(a[0][j], a[1][j], a[2][j], a[3][j]);
            *(float4*)&atile[mq * 4 + j][rq * 4] = v;
        }
        __syncthreads();

        // PV: pv[i][j] += atile[m][rq*4+i] * xtile[m][mq*4+j]
#pragma unroll 8
        for (int m = 0; m < MT; m++) {
            float4 av = *(const float4*)&atile[m][rq * 4];
            float4 xv = *(const float4*)&xtile[m][mq * 4];
            float aa[4] = {av.x, av.y, av.z, av.w};
            float xx[4] = {xv.x, xv.y, xv.z, xv.w};
#pragma unroll
            for (int i = 0; i < 4; i++)
#pragma unroll
                for (int j = 0; j < 4; j++) pv[i][j] = fmaf(aa[i], xx[j], pv[i][j]);
        }
        __syncthreads();
    }

    // epilogue: out[b][c][n] = relu(pv + x), c = mq*4+j, n = n0 + rq*4 + i
#pragma unroll
    for (int i = 0; i < 4; i++) {
#pragma unroll
        for (int j = 0; j < 4; j++) {
            int c = mq * 4 + j;
            int n = n0 + rq * 4 + i;
            size_t idx = ((size_t)(b * CC + c)) * NA + n;
            float v = pv[i][j] + x[idx];
            out[idx] = fmaxf(v, 0.f);
        }
    }
}

extern "C" void kernel_launch(void* const* d_in, const int* in_sizes, int n_in,
                              void* d_out, int out_size, void* d_ws, size_t ws_size,
                              hipStream_t stream) {
    const float* x = (const float*)d_in[0];
    const float* W = (const float*)d_in[1];
    const float* bias = (const float*)d_in[2];

    float* out = (float*)d_out;
    float* alpha = out + (size_t)BB * CC * NA;  // outputs concatenated: out then alpha

    float* g = (float*)d_ws;                       // [B][KA][NA]
    float* norms = g + (size_t)BB * KA * NA;       // [B][NA]
    float* gmaxp = norms + (size_t)BB * NA;        // [B]

    k_g<<<dim3(NA / 256, BB), 256, 0, stream>>>(x, W, bias, g, norms);
    k_gmax<<<BB, 256, 0, stream>>>(norms, gmaxp);
    k_attn<<<dim3(NA / RB, BB), 256, 0, stream>>>(x, g, norms, gmaxp, out, alpha);
}

// Round 2
// 236.226 us; speedup vs baseline: 2.5186x; 2.5186x over previous
//
#include <hip/hip_runtime.h>
#include <math.h>

#define BB 8
#define CC 64
#define NA 4096   // H*W
#define KA 32     // C_a

typedef short bfrag __attribute__((ext_vector_type(8)));   // 8 bf16 = 4 VGPRs
typedef int   i4    __attribute__((ext_vector_type(4)));
typedef float f4    __attribute__((ext_vector_type(4)));
typedef float f16v  __attribute__((ext_vector_type(16)));

__device__ __forceinline__ f16v mf(bfrag a, bfrag b, f16v c) {
    return __builtin_amdgcn_mfma_f32_32x32x16_bf16(a, b, c, 0, 0, 0);
}

// round-to-nearest-even fp32 -> bf16 bits
__device__ __forceinline__ unsigned short bfrne(float f) {
    unsigned u = __builtin_bit_cast(unsigned, f);
    return (unsigned short)((u + 0x7FFFu + ((u >> 16) & 1u)) >> 16);
}
__device__ __forceinline__ unsigned pk2(float a, float b) {
    return (unsigned)bfrne(a) | ((unsigned)bfrne(b) << 16);
}
__device__ __forceinline__ float bf2f(unsigned short h) {
    unsigned u = ((unsigned)h) << 16;
    return __builtin_bit_cast(float, u);
}

// ---------------- Kernel 1: g = W*x + b -> bf16 hi/lo split [b][n][k], norms ----------------
__global__ __launch_bounds__(256) void k_g(const float* __restrict__ x,
                                           const float* __restrict__ W,
                                           const float* __restrict__ bias,
                                           short* __restrict__ ghi,
                                           short* __restrict__ glo,
                                           float* __restrict__ norms) {
    __shared__ float Wl[KA * CC];
    __shared__ float bl[KA];
    int tid = threadIdx.x;
    for (int i = tid; i < KA * CC; i += 256) Wl[i] = W[i];
    if (tid < KA) bl[tid] = bias[tid];
    __syncthreads();

    int b = blockIdx.y;
    int n = blockIdx.x * 256 + tid;

    float acc[KA];
#pragma unroll
    for (int k = 0; k < KA; k++) acc[k] = 0.f;

    const float* xp = x + (size_t)b * CC * NA + n;
#pragma unroll 4
    for (int c = 0; c < CC; c++) {
        float xv = xp[(size_t)c * NA];
#pragma unroll
        for (int k = 0; k < KA; k++) acc[k] = fmaf(Wl[k * CC + c], xv, acc[k]);
    }

    float ss = 0.f;
    unsigned ph[KA / 2], pl[KA / 2];
#pragma unroll
    for (int k = 0; k < KA; k += 2) {
        float v0 = acc[k] + bl[k];
        float v1 = acc[k + 1] + bl[k + 1];
        ss = fmaf(v0, v0, fmaf(v1, v1, ss));
        unsigned short h0 = bfrne(v0), h1 = bfrne(v1);
        float l0 = v0 - bf2f(h0), l1 = v1 - bf2f(h1);
        ph[k / 2] = (unsigned)h0 | ((unsigned)h1 << 16);
        pl[k / 2] = (unsigned)bfrne(l0) | ((unsigned)bfrne(l1) << 16);
    }
    norms[b * NA + n] = sqrtf(ss);

    size_t row = ((size_t)b * NA + n) * KA;  // in shorts
#pragma unroll
    for (int q = 0; q < 4; q++) {
        i4 vh = { (int)ph[4 * q], (int)ph[4 * q + 1], (int)ph[4 * q + 2], (int)ph[4 * q + 3] };
        i4 vl = { (int)pl[4 * q], (int)pl[4 * q + 1], (int)pl[4 * q + 2], (int)pl[4 * q + 3] };
        *(i4*)(ghi + row + q * 8) = vh;
        *(i4*)(glo + row + q * 8) = vl;
    }
}

// ---------------- Kernel 1b: per-batch max norm ----------------
__global__ __launch_bounds__(256) void k_gmax(const float* __restrict__ norms,
                                              float* __restrict__ gmaxp) {
    int b = blockIdx.x, tid = threadIdx.x;
    float m = 0.f;
    for (int i = tid; i < NA; i += 256) m = fmaxf(m, norms[b * NA + i]);
#pragma unroll
    for (int off = 1; off < 64; off <<= 1) m = fmaxf(m, __shfl_xor(m, off));
    __shared__ float red[4];
    if ((tid & 63) == 0) red[tid >> 6] = m;
    __syncthreads();
    if (tid == 0) gmaxp[b] = fmaxf(fmaxf(red[0], red[1]), fmaxf(red[2], red[3]));
}

// ---------------- Kernel 1c: x -> bf16 copy [b][c][m] ----------------
__global__ __launch_bounds__(256) void k_xb(const float* __restrict__ x,
                                            short* __restrict__ xb) {
    size_t idx = ((size_t)blockIdx.x * 256 + threadIdx.x) * 4;
    f4 v = *(const f4*)(x + idx);
    int2 p;
    p.x = (int)pk2(v[0], v[1]);
    p.y = (int)pk2(v[2], v[3]);
    *(int2*)(xb + idx) = p;
}

// per n-tile pass-2 work: alpha = exp(s-M)*L, global fp32 store, bf16 pack + permlane
// swap -> two PV A-fragments (consecutive-m bf16x8).
__device__ __forceinline__ void proc_tile(const f16v& s, float M, float L,
                                          float* __restrict__ aprow, int hi,
                                          bfrag& pa0, bfrag& pa1) {
    float a[16];
#pragma unroll
    for (int r = 0; r < 16; r++) a[r] = __expf(s[r] - M) * L;
#pragma unroll
    for (int q = 0; q < 4; q++) {
        f4 v = { a[4 * q], a[4 * q + 1], a[4 * q + 2], a[4 * q + 3] };
        *(f4*)(aprow + 8 * q + 4 * hi) = v;   // m-run of 4, rows covered by lane pairs
    }
    unsigned p0 = pk2(a[0], a[1]),   p1 = pk2(a[2], a[3]);
    unsigned p2 = pk2(a[4], a[5]),   p3 = pk2(a[6], a[7]);
    unsigned p4 = pk2(a[8], a[9]),   p5 = pk2(a[10], a[11]);
    unsigned p6 = pk2(a[12], a[13]), p7 = pk2(a[14], a[15]);
    // swap upper-half lanes of dst with lower-half lanes of src
    asm("v_permlane32_swap_b32 %0, %1" : "+v"(p0), "+v"(p2));
    asm("v_permlane32_swap_b32 %0, %1" : "+v"(p1), "+v"(p3));
    asm("v_permlane32_swap_b32 %0, %1" : "+v"(p4), "+v"(p6));
    asm("v_permlane32_swap_b32 %0, %1" : "+v"(p5), "+v"(p7));
    i4 f0 = { (int)p0, (int)p1, (int)p2, (int)p3 };
    i4 f1 = { (int)p4, (int)p5, (int)p6, (int)p7 };
    pa0 = __builtin_bit_cast(bfrag, f0);
    pa1 = __builtin_bit_cast(bfrag, f1);
}

// ---------------- Kernel 2: MFMA fused scores -> softmax -> alpha + PV ----------------
__global__ __launch_bounds__(256) void k_attn(const float* __restrict__ x,
                                              const short* __restrict__ ghi,
                                              const short* __restrict__ glo,
                                              const short* __restrict__ xb,
                                              const float* __restrict__ norms,
                                              const float* __restrict__ gmaxp,
                                              float* __restrict__ out,
                                              float* __restrict__ alpha) {
    __shared__ float rowsum[4][64];
    __shared__ float pvred[2][64][65];   // [slot][n][c], +1 pad

    const int tid = threadIdx.x;
    const int w = tid >> 6;
    const int l = tid & 63;
    const int l31 = l & 31;
    const int hi = l >> 5;
    const int b = blockIdx.y;
    const int n0 = blockIdx.x * 64;

    const float gmax = gmaxp[b];
    const float M0 = norms[b * NA + n0 + l31] * gmax;
    const float M1 = norms[b * NA + n0 + 32 + l31] * gmax;

    const short* gh = ghi + (size_t)b * NA * KA;
    const short* gl = glo + (size_t)b * NA * KA;

    // persistent B-fragments: block's 64 rows (n), hi/lo, 2 k-tiles
    bfrag B0h[2], B0l[2], B1h[2], B1l[2];
#pragma unroll
    for (int kt = 0; kt < 2; kt++) {
        size_t o0 = (size_t)(n0 + l31) * KA + kt * 16 + hi * 8;
        size_t o1 = (size_t)(n0 + 32 + l31) * KA + kt * 16 + hi * 8;
        B0h[kt] = *(const bfrag*)(gh + o0);
        B0l[kt] = *(const bfrag*)(gl + o0);
        B1h[kt] = *(const bfrag*)(gh + o1);
        B1l[kt] = *(const bfrag*)(gl + o1);
    }

    // ---------------- pass 1: denominators ----------------
    float ls0 = 0.f, ls1 = 0.f;
    for (int i = 0; i < 32; i++) {
        const int m0 = (i * 4 + w) * 32;
        bfrag Ah[2], Al[2];
#pragma unroll
        for (int kt = 0; kt < 2; kt++) {
            size_t o = (size_t)(m0 + l31) * KA + kt * 16 + hi * 8;
            Ah[kt] = *(const bfrag*)(gh + o);
            Al[kt] = *(const bfrag*)(gl + o);
        }
        f16v s0 = {}, s1 = {};
#pragma unroll
        for (int kt = 0; kt < 2; kt++) {
            s0 = mf(Ah[kt], B0h[kt], s0);
            s1 = mf(Ah[kt], B1h[kt], s1);
            s0 = mf(Ah[kt], B0l[kt], s0);
            s1 = mf(Ah[kt], B1l[kt], s1);
            s0 = mf(Al[kt], B0h[kt], s0);
            s1 = mf(Al[kt], B1h[kt], s1);
        }
#pragma unroll
        for (int r = 0; r < 16; r++) {
            ls0 += __expf(s0[r] - M0);
            ls1 += __expf(s1[r] - M1);
        }
    }
    ls0 += __shfl_xor(ls0, 32);
    ls1 += __shfl_xor(ls1, 32);
    if (hi == 0) rowsum[w][l31] = ls0;
    else         rowsum[w][32 + l31] = ls1;
    __syncthreads();
    const float L0 = 1.f / (rowsum[0][l31] + rowsum[1][l31] + rowsum[2][l31] + rowsum[3][l31]);
    const float L1 = 1.f / (rowsum[0][32 + l31] + rowsum[1][32 + l31] +
                            rowsum[2][32 + l31] + rowsum[3][32 + l31]);

    // ---------------- pass 2: alpha + PV ----------------
    f16v pv00 = {}, pv01 = {}, pv10 = {}, pv11 = {};  // [nt][ct]
    const short* xp = xb + (size_t)b * CC * NA;
    float* ap = alpha + (size_t)b * NA * NA;

    for (int i = 0; i < 32; i++) {
        const int m0 = (i * 4 + w) * 32;
        bfrag Ah[2], Al[2];
#pragma unroll
        for (int kt = 0; kt < 2; kt++) {
            size_t o = (size_t)(m0 + l31) * KA + kt * 16 + hi * 8;
            Ah[kt] = *(const bfrag*)(gh + o);
            Al[kt] = *(const bfrag*)(gl + o);
        }
        f16v s0 = {}, s1 = {};
#pragma unroll
        for (int kt = 0; kt < 2; kt++) {
            s0 = mf(Ah[kt], B0h[kt], s0);
            s1 = mf(Ah[kt], B1h[kt], s1);
            s0 = mf(Ah[kt], B0l[kt], s0);
            s1 = mf(Ah[kt], B1l[kt], s1);
            s0 = mf(Al[kt], B0h[kt], s0);
            s1 = mf(Al[kt], B1h[kt], s1);
        }

        bfrag pa00, pa01, pa10, pa11;
        proc_tile(s0, M0, L0, ap + (size_t)(n0 + l31) * NA + m0, hi, pa00, pa01);
        proc_tile(s1, M1, L1, ap + (size_t)(n0 + 32 + l31) * NA + m0, hi, pa10, pa11);

        // xb B-fragments [ct][kt2]
        size_t ox0 = (size_t)l31 * NA + m0 + hi * 8;
        size_t ox1 = (size_t)(32 + l31) * NA + m0 + hi * 8;
        bfrag X00 = *(const bfrag*)(xp + ox0);
        bfrag X01 = *(const bfrag*)(xp + ox0 + 16);
        bfrag X10 = *(const bfrag*)(xp + ox1);
        bfrag X11 = *(const bfrag*)(xp + ox1 + 16);

        pv00 = mf(pa00, X00, pv00); pv00 = mf(pa01, X01, pv00);
        pv01 = mf(pa00, X10, pv01); pv01 = mf(pa01, X11, pv01);
        pv10 = mf(pa10, X00, pv10); pv10 = mf(pa11, X01, pv10);
        pv11 = mf(pa10, X10, pv11); pv11 = mf(pa11, X11, pv11);
    }

    // ---------------- cross-wave PV reduction ----------------
    if (w >= 2) {
        float (*buf)[65] = pvred[w - 2];
#pragma unroll
        for (int r = 0; r < 16; r++) {
            int nl = (r & 3) + 8 * (r >> 2) + 4 * hi;
            buf[nl][l31]           = pv00[r];
            buf[nl][32 + l31]      = pv01[r];
            buf[32 + nl][l31]      = pv10[r];
            buf[32 + nl][32 + l31] = pv11[r];
        }
    }
    __syncthreads();
    if (w < 2) {
        float (*buf)[65] = pvred[w];
#pragma unroll
        for (int r = 0; r < 16; r++) {
            int nl = (r & 3) + 8 * (r >> 2) + 4 * hi;
            buf[nl][l31]           += pv00[r];
            buf[nl][32 + l31]      += pv01[r];
            buf[32 + nl][l31]      += pv10[r];
            buf[32 + nl][32 + l31] += pv11[r];
        }
    }
    __syncthreads();

    // ---------------- epilogue: residual + relu, coalesced out write ----------------
    const float* xr = x + (size_t)b * CC * NA + n0;
    float* op = out + (size_t)b * CC * NA + n0;
#pragma unroll
    for (int e = 0; e < 16; e++) {
        int idx = e * 256 + tid;
        int c = idx >> 6, n = idx & 63;
        float v = pvred[0][n][c] + pvred[1][n][c] + xr[(size_t)c * NA + n];
        op[(size_t)c * NA + n] = fmaxf(v, 0.f);
    }
}

extern "C" void kernel_launch(void* const* d_in, const int* in_sizes, int n_in,
                              void* d_out, int out_size, void* d_ws, size_t ws_size,
                              hipStream_t stream) {
    const float* x = (const float*)d_in[0];
    const float* W = (const float*)d_in[1];
    const float* bias = (const float*)d_in[2];

    float* out = (float*)d_out;
    float* alpha = out + (size_t)BB * CC * NA;  // outputs concatenated: out then alpha

    short* ghi = (short*)d_ws;                       // [B][NA][KA] bf16 hi
    short* glo = ghi + (size_t)BB * NA * KA;         // bf16 lo
    short* xb  = glo + (size_t)BB * NA * KA;         // [B][CC][NA] bf16
    float* norms = (float*)(xb + (size_t)BB * CC * NA);
    float* gmaxp = norms + (size_t)BB * NA;

    k_g<<<dim3(NA / 256, BB), 256, 0, stream>>>(x, W, bias, ghi, glo, norms);
    k_gmax<<<BB, 256, 0, stream>>>(norms, gmaxp);
    k_xb<<<(BB * CC * NA) / (256 * 4), 256, 0, stream>>>(x, xb);
    k_attn<<<dim3(NA / 64, BB), 256, 0, stream>>>(x, ghi, glo, xb, norms, gmaxp, out, alpha);
}

// Round 3
// 224.814 us; speedup vs baseline: 2.6465x; 1.0508x over previous
//
#include <hip/hip_runtime.h>
#include <math.h>

#define BB 8
#define CC 64
#define NA 4096   // H*W
#define KA 32     // C_a
#define RB 32     // softmax rows per block

typedef short bfrag __attribute__((ext_vector_type(8)));   // 8 bf16 = 4 VGPRs
typedef int   i4    __attribute__((ext_vector_type(4)));
typedef float f4    __attribute__((ext_vector_type(4)));
typedef float f16v  __attribute__((ext_vector_type(16)));

__device__ __forceinline__ f16v mf(bfrag a, bfrag b, f16v c) {
    return __builtin_amdgcn_mfma_f32_32x32x16_bf16(a, b, c, 0, 0, 0);
}

// round-to-nearest-even fp32 -> bf16 bits
__device__ __forceinline__ unsigned short bfrne(float f) {
    unsigned u = __builtin_bit_cast(unsigned, f);
    return (unsigned short)((u + 0x7FFFu + ((u >> 16) & 1u)) >> 16);
}
__device__ __forceinline__ unsigned pk2(float a, float b) {
    return (unsigned)bfrne(a) | ((unsigned)bfrne(b) << 16);
}
__device__ __forceinline__ float bf2f(unsigned short h) {
    unsigned u = ((unsigned)h) << 16;
    return __builtin_bit_cast(float, u);
}

// ---------------- Kernel 1: g = W*x + b -> bf16 hi/lo split [b][n][k], norms ----------------
__global__ __launch_bounds__(256) void k_g(const float* __restrict__ x,
                                           const float* __restrict__ W,
                                           const float* __restrict__ bias,
                                           short* __restrict__ ghi,
                                           short* __restrict__ glo,
                                           float* __restrict__ norms) {
    __shared__ float Wl[KA * CC];
    __shared__ float bl[KA];
    int tid = threadIdx.x;
    for (int i = tid; i < KA * CC; i += 256) Wl[i] = W[i];
    if (tid < KA) bl[tid] = bias[tid];
    __syncthreads();

    int b = blockIdx.y;
    int n = blockIdx.x * 256 + tid;

    float acc[KA];
#pragma unroll
    for (int k = 0; k < KA; k++) acc[k] = 0.f;

    const float* xp = x + (size_t)b * CC * NA + n;
#pragma unroll 4
    for (int c = 0; c < CC; c++) {
        float xv = xp[(size_t)c * NA];
#pragma unroll
        for (int k = 0; k < KA; k++) acc[k] = fmaf(Wl[k * CC + c], xv, acc[k]);
    }

    float ss = 0.f;
    unsigned ph[KA / 2], pl[KA / 2];
#pragma unroll
    for (int k = 0; k < KA; k += 2) {
        float v0 = acc[k] + bl[k];
        float v1 = acc[k + 1] + bl[k + 1];
        ss = fmaf(v0, v0, fmaf(v1, v1, ss));
        unsigned short h0 = bfrne(v0), h1 = bfrne(v1);
        float l0 = v0 - bf2f(h0), l1 = v1 - bf2f(h1);
        ph[k / 2] = (unsigned)h0 | ((unsigned)h1 << 16);
        pl[k / 2] = (unsigned)bfrne(l0) | ((unsigned)bfrne(l1) << 16);
    }
    norms[b * NA + n] = sqrtf(ss);

    size_t row = ((size_t)b * NA + n) * KA;  // in shorts
#pragma unroll
    for (int q = 0; q < 4; q++) {
        i4 vh = { (int)ph[4 * q], (int)ph[4 * q + 1], (int)ph[4 * q + 2], (int)ph[4 * q + 3] };
        i4 vl = { (int)pl[4 * q], (int)pl[4 * q + 1], (int)pl[4 * q + 2], (int)pl[4 * q + 3] };
        *(i4*)(ghi + row + q * 8) = vh;
        *(i4*)(glo + row + q * 8) = vl;
    }
}

// ---------------- Kernel 1b: per-batch max norm ----------------
__global__ __launch_bounds__(256) void k_gmax(const float* __restrict__ norms,
                                              float* __restrict__ gmaxp) {
    int b = blockIdx.x, tid = threadIdx.x;
    float m = 0.f;
    for (int i = tid; i < NA; i += 256) m = fmaxf(m, norms[b * NA + i]);
#pragma unroll
    for (int off = 1; off < 64; off <<= 1) m = fmaxf(m, __shfl_xor(m, off));
    __shared__ float red[4];
    if ((tid & 63) == 0) red[tid >> 6] = m;
    __syncthreads();
    if (tid == 0) gmaxp[b] = fmaxf(fmaxf(red[0], red[1]), fmaxf(red[2], red[3]));
}

// ---------------- Kernel 1c: x -> bf16 copy [b][c][m] ----------------
__global__ __launch_bounds__(256) void k_xb(const float* __restrict__ x,
                                            short* __restrict__ xb) {
    size_t idx = ((size_t)blockIdx.x * 256 + threadIdx.x) * 4;
    f4 v = *(const f4*)(x + idx);
    int2 p;
    p.x = (int)pk2(v[0], v[1]);
    p.y = (int)pk2(v[2], v[3]);
    *(int2*)(xb + idx) = p;
}

// ---------------- Kernel 2: MFMA fused scores -> softmax -> alpha + PV ----------------
// Block = 32 softmax rows (n0..n0+31) of one batch; 4 waves each own one 32-m tile per iter.
// D layout (32x32x16): col=lane&31 -> n, row=(reg&3)+8*(reg>>2)+4*hi -> m.
__global__ __launch_bounds__(256, 3) void k_attn(const float* __restrict__ x,
                                                 const short* __restrict__ ghi,
                                                 const short* __restrict__ glo,
                                                 const short* __restrict__ xb,
                                                 const float* __restrict__ norms,
                                                 const float* __restrict__ gmaxp,
                                                 float* __restrict__ out,
                                                 float* __restrict__ alpha) {
    __shared__ __align__(16) float astage[RB][128];   // 16 KB iter staging, XOR-swizzled f4 chunks
    __shared__ float rowsum[4][RB];
    __shared__ float pvred[2][RB][CC + 1];            // 16.6 KB

    const int tid = threadIdx.x;
    const int w = tid >> 6;
    const int l = tid & 63;
    const int l31 = l & 31;
    const int hi = l >> 5;
    const int b = blockIdx.y;
    const int n0 = blockIdx.x * RB;

    const float M = norms[b * NA + n0 + l31] * gmaxp[b];

    const short* gh = ghi + (size_t)b * NA * KA;
    const short* gl = glo + (size_t)b * NA * KA;

    // persistent B-fragments: block's 32 rows (n), hi/lo, 2 k-tiles
    bfrag Bh[2], Bl[2];
#pragma unroll
    for (int kt = 0; kt < 2; kt++) {
        size_t o = (size_t)(n0 + l31) * KA + kt * 16 + hi * 8;
        Bh[kt] = *(const bfrag*)(gh + o);
        Bl[kt] = *(const bfrag*)(gl + o);
    }

    // ---------------- pass 1: denominators ----------------
    float ls = 0.f;
    for (int i = 0; i < 32; i++) {
        const int m0 = i * 128 + w * 32;
        bfrag Ah[2], Al[2];
#pragma unroll
        for (int kt = 0; kt < 2; kt++) {
            size_t o = (size_t)(m0 + l31) * KA + kt * 16 + hi * 8;
            Ah[kt] = *(const bfrag*)(gh + o);
            Al[kt] = *(const bfrag*)(gl + o);
        }
        f16v s = {};
#pragma unroll
        for (int kt = 0; kt < 2; kt++) {
            s = mf(Ah[kt], Bh[kt], s);
            s = mf(Ah[kt], Bl[kt], s);
            s = mf(Al[kt], Bh[kt], s);
        }
#pragma unroll
        for (int r = 0; r < 16; r++) ls += __expf(s[r] - M);
    }
    ls += __shfl_xor(ls, 32);
    if (hi == 0) rowsum[w][l31] = ls;
    __syncthreads();
    const float L = 1.f / (rowsum[0][l31] + rowsum[1][l31] + rowsum[2][l31] + rowsum[3][l31]);

    // ---------------- pass 2: alpha + PV ----------------
    f16v pv0 = {}, pv1 = {};
    const short* xp = xb + (size_t)b * CC * NA;
    float* ap = alpha + (size_t)b * NA * NA;

    for (int i = 0; i < 32; i++) {
        const int m0 = i * 128 + w * 32;
        bfrag Ah[2], Al[2];
#pragma unroll
        for (int kt = 0; kt < 2; kt++) {
            size_t o = (size_t)(m0 + l31) * KA + kt * 16 + hi * 8;
            Ah[kt] = *(const bfrag*)(gh + o);
            Al[kt] = *(const bfrag*)(gl + o);
        }
        f16v s = {};
#pragma unroll
        for (int kt = 0; kt < 2; kt++) {
            s = mf(Ah[kt], Bh[kt], s);
            s = mf(Ah[kt], Bl[kt], s);
            s = mf(Al[kt], Bh[kt], s);
        }

        float a[16];
#pragma unroll
        for (int r = 0; r < 16; r++) a[r] = __expf(s[r] - M) * L;

        // stage alpha tile in LDS (XOR-swizzled f4 chunks), coalesced store after barrier
#pragma unroll
        for (int q = 0; q < 4; q++) {
            f4 v = { a[4 * q], a[4 * q + 1], a[4 * q + 2], a[4 * q + 3] };
            int clog = w * 8 + 2 * q + hi;
            int phys = clog ^ (l31 & 7);
            *(f4*)&astage[l31][phys * 4] = v;
        }

        // pack P -> bf16 A-fragments via permlane32_swap (verified round-2 recipe)
        unsigned p0 = pk2(a[0], a[1]),   p1 = pk2(a[2], a[3]);
        unsigned p2 = pk2(a[4], a[5]),   p3 = pk2(a[6], a[7]);
        unsigned p4 = pk2(a[8], a[9]),   p5 = pk2(a[10], a[11]);
        unsigned p6 = pk2(a[12], a[13]), p7 = pk2(a[14], a[15]);
        asm("v_permlane32_swap_b32 %0, %1" : "+v"(p0), "+v"(p2));
        asm("v_permlane32_swap_b32 %0, %1" : "+v"(p1), "+v"(p3));
        asm("v_permlane32_swap_b32 %0, %1" : "+v"(p4), "+v"(p6));
        asm("v_permlane32_swap_b32 %0, %1" : "+v"(p5), "+v"(p7));
        i4 f0 = { (int)p0, (int)p1, (int)p2, (int)p3 };
        i4 f1 = { (int)p4, (int)p5, (int)p6, (int)p7 };
        bfrag pa0 = __builtin_bit_cast(bfrag, f0);
        bfrag pa1 = __builtin_bit_cast(bfrag, f1);

        // X B-fragments: lane = channel c, regs = m-slice
        size_t ox0 = (size_t)l31 * NA + m0 + hi * 8;
        size_t ox1 = (size_t)(32 + l31) * NA + m0 + hi * 8;
        bfrag X00 = *(const bfrag*)(xp + ox0);
        bfrag X01 = *(const bfrag*)(xp + ox0 + 16);
        bfrag X10 = *(const bfrag*)(xp + ox1);
        bfrag X11 = *(const bfrag*)(xp + ox1 + 16);

        pv0 = mf(pa0, X00, pv0); pv0 = mf(pa1, X01, pv0);
        pv1 = mf(pa0, X10, pv1); pv1 = mf(pa1, X11, pv1);

        __syncthreads();
        // coalesced alpha store: each inst covers 2 full rows x 512B
#pragma unroll
        for (int e = 0; e < 4; e++) {
            int row = e * 8 + (tid >> 5);
            int clog = tid & 31;
            int phys = clog ^ (row & 7);
            f4 v = *(const f4*)&astage[row][phys * 4];
            *(f4*)(ap + (size_t)(n0 + row) * NA + i * 128 + clog * 4) = v;
        }
        __syncthreads();
    }

    // ---------------- cross-wave PV reduction ----------------
    if (w >= 2) {
        float (*buf)[CC + 1] = pvred[w - 2];
#pragma unroll
        for (int r = 0; r < 16; r++) {
            int nl = (r & 3) + 8 * (r >> 2) + 4 * hi;
            buf[nl][l31]      = pv0[r];
            buf[nl][32 + l31] = pv1[r];
        }
    }
    __syncthreads();
    if (w < 2) {
        float (*buf)[CC + 1] = pvred[w];
#pragma unroll
        for (int r = 0; r < 16; r++) {
            int nl = (r & 3) + 8 * (r >> 2) + 4 * hi;
            buf[nl][l31]      += pv0[r];
            buf[nl][32 + l31] += pv1[r];
        }
    }
    __syncthreads();

    // ---------------- epilogue: residual + relu ----------------
    const float* xr = x + (size_t)b * CC * NA + n0;
    float* op = out + (size_t)b * CC * NA + n0;
#pragma unroll
    for (int e = 0; e < 8; e++) {
        int idx = e * 256 + tid;
        int c = idx >> 5, n = idx & 31;
        float v = pvred[0][n][c] + pvred[1][n][c] + xr[(size_t)c * NA + n];
        op[(size_t)c * NA + n] = fmaxf(v, 0.f);
    }
}

extern "C" void kernel_launch(void* const* d_in, const int* in_sizes, int n_in,
                              void* d_out, int out_size, void* d_ws, size_t ws_size,
                              hipStream_t stream) {
    const float* x = (const float*)d_in[0];
    const float* W = (const float*)d_in[1];
    const float* bias = (const float*)d_in[2];

    float* out = (float*)d_out;
    float* alpha = out + (size_t)BB * CC * NA;  // outputs concatenated: out then alpha

    short* ghi = (short*)d_ws;                       // [B][NA][KA] bf16 hi
    short* glo = ghi + (size_t)BB * NA * KA;         // bf16 lo
    short* xb  = glo + (size_t)BB * NA * KA;         // [B][CC][NA] bf16
    float* norms = (float*)(xb + (size_t)BB * CC * NA);
    float* gmaxp = norms + (size_t)BB * NA;

    k_g<<<dim3(NA / 256, BB), 256, 0, stream>>>(x, W, bias, ghi, glo, norms);
    k_gmax<<<BB, 256, 0, stream>>>(norms, gmaxp);
    k_xb<<<(BB * CC * NA) / (256 * 4), 256, 0, stream>>>(x, xb);
    k_attn<<<dim3(NA / RB, BB), 256, 0, stream>>>(x, ghi, glo, xb, norms, gmaxp, out, alpha);
}

// Round 4
// 221.994 us; speedup vs baseline: 2.6801x; 1.0127x over previous
//
#include <hip/hip_runtime.h>
#include <math.h>

#define BB 8
#define CC 64
#define NA 4096   // H*W
#define KA 32     // C_a
#define LOG2E 1.4426950408889634f

typedef short bfrag __attribute__((ext_vector_type(8)));   // 8 bf16 = 4 VGPRs
typedef int   i4    __attribute__((ext_vector_type(4)));
typedef float f4    __attribute__((ext_vector_type(4)));
typedef float f16v  __attribute__((ext_vector_type(16)));

__device__ __forceinline__ f16v mf(bfrag a, bfrag b, f16v c) {
    return __builtin_amdgcn_mfma_f32_32x32x16_bf16(a, b, c, 0, 0, 0);
}

// round-to-nearest-even fp32 -> bf16 bits
__device__ __forceinline__ unsigned short bfrne(float f) {
    unsigned u = __builtin_bit_cast(unsigned, f);
    return (unsigned short)((u + 0x7FFFu + ((u >> 16) & 1u)) >> 16);
}
__device__ __forceinline__ unsigned pk2(float a, float b) {
    return (unsigned)bfrne(a) | ((unsigned)bfrne(b) << 16);
}
__device__ __forceinline__ float bf2f(unsigned short h) {
    unsigned u = ((unsigned)h) << 16;
    return __builtin_bit_cast(float, u);
}

// ---------------- Kernel 1: g = W*x + b -> bf16 hi/lo split [b][n][k], norms ----------------
__global__ __launch_bounds__(256) void k_g(const float* __restrict__ x,
                                           const float* __restrict__ W,
                                           const float* __restrict__ bias,
                                           short* __restrict__ ghi,
                                           short* __restrict__ glo,
                                           float* __restrict__ norms) {
    __shared__ float Wl[KA * CC];
    __shared__ float bl[KA];
    int tid = threadIdx.x;
    for (int i = tid; i < KA * CC; i += 256) Wl[i] = W[i];
    if (tid < KA) bl[tid] = bias[tid];
    __syncthreads();

    int b = blockIdx.y;
    int n = blockIdx.x * 256 + tid;

    float acc[KA];
#pragma unroll
    for (int k = 0; k < KA; k++) acc[k] = 0.f;

    const float* xp = x + (size_t)b * CC * NA + n;
#pragma unroll 4
    for (int c = 0; c < CC; c++) {
        float xv = xp[(size_t)c * NA];
#pragma unroll
        for (int k = 0; k < KA; k++) acc[k] = fmaf(Wl[k * CC + c], xv, acc[k]);
    }

    float ss = 0.f;
    unsigned ph[KA / 2], pl[KA / 2];
#pragma unroll
    for (int k = 0; k < KA; k += 2) {
        float v0 = acc[k] + bl[k];
        float v1 = acc[k + 1] + bl[k + 1];
        ss = fmaf(v0, v0, fmaf(v1, v1, ss));
        unsigned short h0 = bfrne(v0), h1 = bfrne(v1);
        float l0 = v0 - bf2f(h0), l1 = v1 - bf2f(h1);
        ph[k / 2] = (unsigned)h0 | ((unsigned)h1 << 16);
        pl[k / 2] = (unsigned)bfrne(l0) | ((unsigned)bfrne(l1) << 16);
    }
    norms[b * NA + n] = sqrtf(ss);

    size_t row = ((size_t)b * NA + n) * KA;  // in shorts
#pragma unroll
    for (int q = 0; q < 4; q++) {
        i4 vh = { (int)ph[4 * q], (int)ph[4 * q + 1], (int)ph[4 * q + 2], (int)ph[4 * q + 3] };
        i4 vl = { (int)pl[4 * q], (int)pl[4 * q + 1], (int)pl[4 * q + 2], (int)pl[4 * q + 3] };
        *(i4*)(ghi + row + q * 8) = vh;
        *(i4*)(glo + row + q * 8) = vl;
    }
}

// ---------------- Kernel 1b: per-batch max norm ----------------
__global__ __launch_bounds__(256) void k_gmax(const float* __restrict__ norms,
                                              float* __restrict__ gmaxp) {
    int b = blockIdx.x, tid = threadIdx.x;
    float m = 0.f;
    for (int i = tid; i < NA; i += 256) m = fmaxf(m, norms[b * NA + i]);
#pragma unroll
    for (int off = 1; off < 64; off <<= 1) m = fmaxf(m, __shfl_xor(m, off));
    __shared__ float red[4];
    if ((tid & 63) == 0) red[tid >> 6] = m;
    __syncthreads();
    if (tid == 0) gmaxp[b] = fmaxf(fmaxf(red[0], red[1]), fmaxf(red[2], red[3]));
}

// ---------------- Kernel 1c: x -> bf16 copy [b][c][m] ----------------
__global__ __launch_bounds__(256) void k_xb(const float* __restrict__ x,
                                            short* __restrict__ xb) {
    size_t idx = ((size_t)blockIdx.x * 256 + threadIdx.x) * 4;
    f4 v = *(const f4*)(x + idx);
    int2 p;
    p.x = (int)pk2(v[0], v[1]);
    p.y = (int)pk2(v[2], v[3]);
    *(int2*)(xb + idx) = p;
}

// ---------------- Kernel 2a: denominators (pass 1), m-split x4 ----------------
// grid 4096: b = id&7 (XCD), nb = (id>>3)&127 (32-row n-tile), mc = id>>10 (m-quarter)
__global__ __launch_bounds__(256, 4) void k_den(const short* __restrict__ ghi,
                                                const short* __restrict__ glo,
                                                const float* __restrict__ norms,
                                                const float* __restrict__ gmaxp,
                                                float* __restrict__ partial) {
    __shared__ float rowsum[4][32];
    const int tid = threadIdx.x;
    const int w = tid >> 6;
    const int l31 = tid & 31;
    const int hi = (tid >> 5) & 1;
    const int id = blockIdx.x;
    const int b = id & 7;
    const int rr = id >> 3;
    const int nb = rr & 127;
    const int mc = rr >> 7;
    const int n0 = nb * 32;

    const float C2 = -norms[b * NA + n0 + l31] * gmaxp[b] * LOG2E;
    const short* gh = ghi + (size_t)b * NA * KA;
    const short* gl = glo + (size_t)b * NA * KA;

    bfrag Bh[2], Bl[2];
#pragma unroll
    for (int kt = 0; kt < 2; kt++) {
        size_t o = (size_t)(n0 + l31) * KA + kt * 16 + hi * 8;
        Bh[kt] = *(const bfrag*)(gh + o);
        Bl[kt] = *(const bfrag*)(gl + o);
    }

    float ls = 0.f;
#pragma unroll 2
    for (int i = 0; i < 8; i++) {
        const int m0 = (mc * 8 + i) * 128 + w * 32;
        bfrag Ah[2], Al[2];
#pragma unroll
        for (int kt = 0; kt < 2; kt++) {
            size_t o = (size_t)(m0 + l31) * KA + kt * 16 + hi * 8;
            Ah[kt] = *(const bfrag*)(gh + o);
            Al[kt] = *(const bfrag*)(gl + o);
        }
        f16v sA = {}, sB = {};
        sA = mf(Ah[0], Bh[0], sA); sA = mf(Ah[1], Bh[1], sA);
        sB = mf(Ah[0], Bl[0], sB); sB = mf(Ah[1], Bl[1], sB);
        sB = mf(Al[0], Bh[0], sB); sB = mf(Al[1], Bh[1], sB);
#pragma unroll
        for (int r = 0; r < 16; r++) ls += exp2f(fmaf(sA[r] + sB[r], LOG2E, C2));
    }
    ls += __shfl_xor(ls, 32);
    if (hi == 0) rowsum[w][l31] = ls;
    __syncthreads();
    if (tid < 32)
        partial[((size_t)mc * BB + b) * NA + n0 + tid] =
            rowsum[0][tid] + rowsum[1][tid] + rowsum[2][tid] + rowsum[3][tid];
}

// ---------------- Kernel 2b: reduce partials -> 1/L ----------------
__global__ __launch_bounds__(256) void k_red(const float* __restrict__ partial,
                                             float* __restrict__ linv) {
    int i = blockIdx.x * 256 + threadIdx.x;
    const size_t S = (size_t)BB * NA;
    linv[i] = 1.f / (partial[i] + partial[S + i] + partial[2 * S + i] + partial[3 * S + i]);
}

// ---------------- Kernel 3: pass 2 — alpha + PV, x-tile LDS-staged ----------------
// grid 1024: b = id&7 (XCD-pinned batch), nb = id>>3 (32-row n-tile)
__global__ __launch_bounds__(256, 3) void k_attn2(const float* __restrict__ x,
                                                  const short* __restrict__ ghi,
                                                  const short* __restrict__ glo,
                                                  const short* __restrict__ xb,
                                                  const float* __restrict__ norms,
                                                  const float* __restrict__ gmaxp,
                                                  const float* __restrict__ linv,
                                                  float* __restrict__ out,
                                                  float* __restrict__ alpha) {
    // smem: xtile dbuf [2][64 rows c][136 shorts] (272B rows, 16B-aligned) = 34816 B
    //       astage [32][128] f32 = 16384 B; pvred aliases whole block in epilogue
    __shared__ __align__(16) char smem[34816 + 16384];
    short* xt = (short*)smem;
    float* ast = (float*)(smem + 34816);

    const int tid = threadIdx.x;
    const int w = tid >> 6;
    const int l31 = tid & 31;
    const int hi = (tid >> 5) & 1;
    const int id = blockIdx.x;
    const int b = id & 7;
    const int n0 = (id >> 3) * 32;

    const float M = norms[b * NA + n0 + l31] * gmaxp[b];
    const float C2 = -M * LOG2E;
    const float L = linv[b * NA + n0 + l31];

    const short* gh = ghi + (size_t)b * NA * KA;
    const short* gl = glo + (size_t)b * NA * KA;
    const short* xp = xb + (size_t)b * CC * NA;
    float* ap = alpha + (size_t)b * NA * NA;

    // persistent B-fragments (block rows n)
    bfrag Bh[2], Bl[2];
#pragma unroll
    for (int kt = 0; kt < 2; kt++) {
        size_t o = (size_t)(n0 + l31) * KA + kt * 16 + hi * 8;
        Bh[kt] = *(const bfrag*)(gh + o);
        Bl[kt] = *(const bfrag*)(gl + o);
    }

    // x-stage thread mapping: row c = tid>>2, sub = tid&3 (64B sub-chunk)
    const int sc = tid >> 2, ss = tid & 3;

    // prologue: tile 0 -> regs -> xtile[0]; A-frags for iter 0
    i4 xs[4];
    {
        const short* src = xp + (size_t)sc * NA;
#pragma unroll
        for (int i = 0; i < 4; i++) xs[i] = *(const i4*)(src + ss * 32 + i * 8);
    }
    bfrag Ah[2], Al[2];
#pragma unroll
    for (int kt = 0; kt < 2; kt++) {
        size_t o = (size_t)(w * 32 + l31) * KA + kt * 16 + hi * 8;
        Ah[kt] = *(const bfrag*)(gh + o);
        Al[kt] = *(const bfrag*)(gl + o);
    }
#pragma unroll
    for (int i = 0; i < 4; i++) *(i4*)(xt + sc * 136 + ss * 32 + i * 8) = xs[i];
    __syncthreads();

    f16v pv0 = {}, pv1 = {};
    int cur = 0;

    for (int it = 0; it < 32; ++it) {
        // ---- epoch A: scores + exp + astage; prefetch next A + next x-tile ----
        // issue next x-tile loads early (consumed after bar1)
        if (it < 31) {
            const short* src = xp + (size_t)sc * NA + (it + 1) * 128;
#pragma unroll
            for (int i = 0; i < 4; i++) xs[i] = *(const i4*)(src + ss * 32 + i * 8);
        }
        f16v sA = {}, sB = {};
        sA = mf(Ah[0], Bh[0], sA); sA = mf(Ah[1], Bh[1], sA);
        sB = mf(Ah[0], Bl[0], sB); sB = mf(Ah[1], Bl[1], sB);
        sB = mf(Al[0], Bh[0], sB); sB = mf(Al[1], Bh[1], sB);
        // prefetch next iteration's A-frags (drained at bar1)
        if (it < 31) {
            const int m0n = (it + 1) * 128 + w * 32;
#pragma unroll
            for (int kt = 0; kt < 2; kt++) {
                size_t o = (size_t)(m0n + l31) * KA + kt * 16 + hi * 8;
                Ah[kt] = *(const bfrag*)(gh + o);
                Al[kt] = *(const bfrag*)(gl + o);
            }
        }
        float a[16];
#pragma unroll
        for (int r = 0; r < 16; r++) a[r] = exp2f(fmaf(sA[r] + sB[r], LOG2E, C2)) * L;
        // astage (swizzled 16B chunks)
#pragma unroll
        for (int q = 0; q < 4; q++) {
            f4 v = { a[4 * q], a[4 * q + 1], a[4 * q + 2], a[4 * q + 3] };
            int phys = (w * 8 + 2 * q + hi) ^ (l31 & 7);
            *(f4*)&ast[l31 * 128 + phys * 4] = v;
        }
        __syncthreads();   // bar1: astage visible; prefetches drained

        // ---- epoch B: alpha store, pack+PV, write next x-tile ----
#pragma unroll
        for (int e = 0; e < 4; e++) {
            int row = e * 8 + (tid >> 5);
            int clog = tid & 31;
            int phys = clog ^ (row & 7);
            f4 v = *(const f4*)&ast[row * 128 + phys * 4];
            *(f4*)(ap + (size_t)(n0 + row) * NA + it * 128 + clog * 4) = v;
        }

        unsigned p0 = pk2(a[0], a[1]),   p1 = pk2(a[2], a[3]);
        unsigned p2 = pk2(a[4], a[5]),   p3 = pk2(a[6], a[7]);
        unsigned p4 = pk2(a[8], a[9]),   p5 = pk2(a[10], a[11]);
        unsigned p6 = pk2(a[12], a[13]), p7 = pk2(a[14], a[15]);
        asm("v_permlane32_swap_b32 %0, %1" : "+v"(p0), "+v"(p2));
        asm("v_permlane32_swap_b32 %0, %1" : "+v"(p1), "+v"(p3));
        asm("v_permlane32_swap_b32 %0, %1" : "+v"(p4), "+v"(p6));
        asm("v_permlane32_swap_b32 %0, %1" : "+v"(p5), "+v"(p7));
        i4 f0 = { (int)p0, (int)p1, (int)p2, (int)p3 };
        i4 f1 = { (int)p4, (int)p5, (int)p6, (int)p7 };
        bfrag pa0 = __builtin_bit_cast(bfrag, f0);
        bfrag pa1 = __builtin_bit_cast(bfrag, f1);

        const short* xc = xt + cur * 8704;
        bfrag X00 = *(const bfrag*)(xc + l31 * 136 + w * 32 + hi * 8);
        bfrag X01 = *(const bfrag*)(xc + l31 * 136 + w * 32 + hi * 8 + 16);
        pv0 = mf(pa0, X00, pv0); pv0 = mf(pa1, X01, pv0);
        bfrag X10 = *(const bfrag*)(xc + (32 + l31) * 136 + w * 32 + hi * 8);
        bfrag X11 = *(const bfrag*)(xc + (32 + l31) * 136 + w * 32 + hi * 8 + 16);
        pv1 = mf(pa0, X10, pv1); pv1 = mf(pa1, X11, pv1);

        if (it < 31) {
            short* xn = xt + (cur ^ 1) * 8704;
#pragma unroll
            for (int i = 0; i < 4; i++) *(i4*)(xn + sc * 136 + ss * 32 + i * 8) = xs[i];
        }
        __syncthreads();   // bar2: next tile ready; astage free for next write
        cur ^= 1;
    }

    // ---------------- cross-wave PV reduction (alias smem) ----------------
    float (*pvr0)[CC + 1] = (float(*)[CC + 1])smem;
    float (*pvr1)[CC + 1] = (float(*)[CC + 1])(smem + 32 * (CC + 1) * 4);
    if (w >= 2) {
        float (*buf)[CC + 1] = (w == 2) ? pvr0 : pvr1;
#pragma unroll
        for (int r = 0; r < 16; r++) {
            int nl = (r & 3) + 8 * (r >> 2) + 4 * hi;
            buf[nl][l31]      = pv0[r];
            buf[nl][32 + l31] = pv1[r];
        }
    }
    __syncthreads();
    if (w < 2) {
        float (*buf)[CC + 1] = (w == 0) ? pvr0 : pvr1;
#pragma unroll
        for (int r = 0; r < 16; r++) {
            int nl = (r & 3) + 8 * (r >> 2) + 4 * hi;
            buf[nl][l31]      += pv0[r];
            buf[nl][32 + l31] += pv1[r];
        }
    }
    __syncthreads();

    // ---------------- epilogue: residual + relu ----------------
    const float* xr = x + (size_t)b * CC * NA + n0;
    float* op = out + (size_t)b * CC * NA + n0;
#pragma unroll
    for (int e = 0; e < 8; e++) {
        int idx = e * 256 + tid;
        int c = idx >> 5, n = idx & 31;
        float v = pvr0[n][c] + pvr1[n][c] + xr[(size_t)c * NA + n];
        op[(size_t)c * NA + n] = fmaxf(v, 0.f);
    }
}

extern "C" void kernel_launch(void* const* d_in, const int* in_sizes, int n_in,
                              void* d_out, int out_size, void* d_ws, size_t ws_size,
                              hipStream_t stream) {
    const float* x = (const float*)d_in[0];
    const float* W = (const float*)d_in[1];
    const float* bias = (const float*)d_in[2];

    float* out = (float*)d_out;
    float* alpha = out + (size_t)BB * CC * NA;  // outputs concatenated: out then alpha

    short* ghi = (short*)d_ws;                       // [B][NA][KA] bf16 hi
    short* glo = ghi + (size_t)BB * NA * KA;         // bf16 lo
    short* xb  = glo + (size_t)BB * NA * KA;         // [B][CC][NA] bf16
    float* norms = (float*)(xb + (size_t)BB * CC * NA);
    float* gmaxp = norms + (size_t)BB * NA;
    float* partial = gmaxp + BB;                     // [4][B][NA]
    float* linv = partial + (size_t)4 * BB * NA;     // [B][NA]

    k_g<<<dim3(NA / 256, BB), 256, 0, stream>>>(x, W, bias, ghi, glo, norms);
    k_gmax<<<BB, 256, 0, stream>>>(norms, gmaxp);
    k_xb<<<(BB * CC * NA) / (256 * 4), 256, 0, stream>>>(x, xb);
    k_den<<<4096, 256, 0, stream>>>(ghi, glo, norms, gmaxp, partial);
    k_red<<<BB * NA / 256, 256, 0, stream>>>(partial, linv);
    k_attn2<<<1024, 256, 0, stream>>>(x, ghi, glo, xb, norms, gmaxp, linv, out, alpha);
}

// Round 5
// 201.350 us; speedup vs baseline: 2.9549x; 1.1025x over previous
//
#include <hip/hip_runtime.h>
#include <math.h>

#define BB 8
#define CC 64
#define NA 4096   // H*W
#define KA 32     // C_a
#define LOG2E 1.4426950408889634f

typedef short bfrag __attribute__((ext_vector_type(8)));   // 8 bf16 = 4 VGPRs
typedef int   i4    __attribute__((ext_vector_type(4)));
typedef float f4    __attribute__((ext_vector_type(4)));
typedef float f16v  __attribute__((ext_vector_type(16)));

__device__ __forceinline__ f16v mf(bfrag a, bfrag b, f16v c) {
    return __builtin_amdgcn_mfma_f32_32x32x16_bf16(a, b, c, 0, 0, 0);
}

// round-to-nearest-even fp32 -> bf16 bits
__device__ __forceinline__ unsigned short bfrne(float f) {
    unsigned u = __builtin_bit_cast(unsigned, f);
    return (unsigned short)((u + 0x7FFFu + ((u >> 16) & 1u)) >> 16);
}
__device__ __forceinline__ unsigned pk2(float a, float b) {
    return (unsigned)bfrne(a) | ((unsigned)bfrne(b) << 16);
}
__device__ __forceinline__ float bf2f(unsigned short h) {
    unsigned u = ((unsigned)h) << 16;
    return __builtin_bit_cast(float, u);
}

// ---------------- Kernel 1: g = W*x + b -> bf16 hi/lo split [b][n][k], norms ----------------
__global__ __launch_bounds__(256) void k_g(const float* __restrict__ x,
                                           const float* __restrict__ W,
                                           const float* __restrict__ bias,
                                           short* __restrict__ ghi,
                                           short* __restrict__ glo,
                                           float* __restrict__ norms) {
    __shared__ float Wl[KA * CC];
    __shared__ float bl[KA];
    int tid = threadIdx.x;
    for (int i = tid; i < KA * CC; i += 256) Wl[i] = W[i];
    if (tid < KA) bl[tid] = bias[tid];
    __syncthreads();

    int b = blockIdx.y;
    int n = blockIdx.x * 256 + tid;

    float acc[KA];
#pragma unroll
    for (int k = 0; k < KA; k++) acc[k] = 0.f;

    const float* xp = x + (size_t)b * CC * NA + n;
#pragma unroll 4
    for (int c = 0; c < CC; c++) {
        float xv = xp[(size_t)c * NA];
#pragma unroll
        for (int k = 0; k < KA; k++) acc[k] = fmaf(Wl[k * CC + c], xv, acc[k]);
    }

    float ss = 0.f;
    unsigned ph[KA / 2], pl[KA / 2];
#pragma unroll
    for (int k = 0; k < KA; k += 2) {
        float v0 = acc[k] + bl[k];
        float v1 = acc[k + 1] + bl[k + 1];
        ss = fmaf(v0, v0, fmaf(v1, v1, ss));
        unsigned short h0 = bfrne(v0), h1 = bfrne(v1);
        float l0 = v0 - bf2f(h0), l1 = v1 - bf2f(h1);
        ph[k / 2] = (unsigned)h0 | ((unsigned)h1 << 16);
        pl[k / 2] = (unsigned)bfrne(l0) | ((unsigned)bfrne(l1) << 16);
    }
    norms[b * NA + n] = sqrtf(ss);

    size_t row = ((size_t)b * NA + n) * KA;  // in shorts
#pragma unroll
    for (int q = 0; q < 4; q++) {
        i4 vh = { (int)ph[4 * q], (int)ph[4 * q + 1], (int)ph[4 * q + 2], (int)ph[4 * q + 3] };
        i4 vl = { (int)pl[4 * q], (int)pl[4 * q + 1], (int)pl[4 * q + 2], (int)pl[4 * q + 3] };
        *(i4*)(ghi + row + q * 8) = vh;
        *(i4*)(glo + row + q * 8) = vl;
    }
}

// ---------------- Kernel 1b: per-batch max norm ----------------
__global__ __launch_bounds__(256) void k_gmax(const float* __restrict__ norms,
                                              float* __restrict__ gmaxp) {
    int b = blockIdx.x, tid = threadIdx.x;
    float m = 0.f;
    for (int i = tid; i < NA; i += 256) m = fmaxf(m, norms[b * NA + i]);
#pragma unroll
    for (int off = 1; off < 64; off <<= 1) m = fmaxf(m, __shfl_xor(m, off));
    __shared__ float red[4];
    if ((tid & 63) == 0) red[tid >> 6] = m;
    __syncthreads();
    if (tid == 0) gmaxp[b] = fmaxf(fmaxf(red[0], red[1]), fmaxf(red[2], red[3]));
}

// ---------------- Kernel 1c: x -> bf16 copy [b][c][m] ----------------
__global__ __launch_bounds__(256) void k_xb(const float* __restrict__ x,
                                            short* __restrict__ xb) {
    size_t idx = ((size_t)blockIdx.x * 256 + threadIdx.x) * 4;
    f4 v = *(const f4*)(x + idx);
    int2 p;
    p.x = (int)pk2(v[0], v[1]);
    p.y = (int)pk2(v[2], v[3]);
    *(int2*)(xb + idx) = p;
}

// ---------------- Kernel 2a: denominators (pass 1), m-split x4 ----------------
__global__ __launch_bounds__(256, 4) void k_den(const short* __restrict__ ghi,
                                                const short* __restrict__ glo,
                                                const float* __restrict__ norms,
                                                const float* __restrict__ gmaxp,
                                                float* __restrict__ partial) {
    __shared__ float rowsum[4][32];
    const int tid = threadIdx.x;
    const int w = tid >> 6;
    const int l31 = tid & 31;
    const int hi = (tid >> 5) & 1;
    const int id = blockIdx.x;
    const int b = id & 7;
    const int rr = id >> 3;
    const int nb = rr & 127;
    const int mc = rr >> 7;
    const int n0 = nb * 32;

    const float C2 = -norms[b * NA + n0 + l31] * gmaxp[b] * LOG2E;
    const short* gh = ghi + (size_t)b * NA * KA;
    const short* gl = glo + (size_t)b * NA * KA;

    bfrag Bh[2], Bl[2];
#pragma unroll
    for (int kt = 0; kt < 2; kt++) {
        size_t o = (size_t)(n0 + l31) * KA + kt * 16 + hi * 8;
        Bh[kt] = *(const bfrag*)(gh + o);
        Bl[kt] = *(const bfrag*)(gl + o);
    }

    float ls = 0.f;
#pragma unroll 2
    for (int i = 0; i < 8; i++) {
        const int m0 = (mc * 8 + i) * 128 + w * 32;
        bfrag Ah[2], Al[2];
#pragma unroll
        for (int kt = 0; kt < 2; kt++) {
            size_t o = (size_t)(m0 + l31) * KA + kt * 16 + hi * 8;
            Ah[kt] = *(const bfrag*)(gh + o);
            Al[kt] = *(const bfrag*)(gl + o);
        }
        f16v sA = {}, sB = {};
        sA = mf(Ah[0], Bh[0], sA); sA = mf(Ah[1], Bh[1], sA);
        sB = mf(Ah[0], Bl[0], sB); sB = mf(Ah[1], Bl[1], sB);
        sB = mf(Al[0], Bh[0], sB); sB = mf(Al[1], Bh[1], sB);
#pragma unroll
        for (int r = 0; r < 16; r++) ls += exp2f(fmaf(sA[r] + sB[r], LOG2E, C2));
    }
    ls += __shfl_xor(ls, 32);
    if (hi == 0) rowsum[w][l31] = ls;
    __syncthreads();
    if (tid < 32)
        partial[((size_t)mc * BB + b) * NA + n0 + tid] =
            rowsum[0][tid] + rowsum[1][tid] + rowsum[2][tid] + rowsum[3][tid];
}

// ---------------- Kernel 2b: reduce partials -> 1/L ----------------
__global__ __launch_bounds__(256) void k_red(const float* __restrict__ partial,
                                             float* __restrict__ linv) {
    int i = blockIdx.x * 256 + threadIdx.x;
    const size_t S = (size_t)BB * NA;
    linv[i] = 1.f / (partial[i] + partial[S + i] + partial[2 * S + i] + partial[3 * S + i]);
}

// ---------------- Kernel 3: pass 2 — alpha + PV ----------------
// MT=256 m per iter (16 iters), astage double-buffered, ONE barrier per iter:
// fill(buf) -> bar -> issue nt stores(buf) -> fill(buf^1) overlaps store drain.
// grid 1024: b = id&7 (XCD-pinned batch), n0 = (id>>3)*32
__global__ __launch_bounds__(256, 2) void k_attn2(const float* __restrict__ x,
                                                  const short* __restrict__ ghi,
                                                  const short* __restrict__ glo,
                                                  const short* __restrict__ xb,
                                                  const float* __restrict__ norms,
                                                  const float* __restrict__ gmaxp,
                                                  const float* __restrict__ linv,
                                                  float* __restrict__ out,
                                                  float* __restrict__ alpha) {
    __shared__ __align__(16) char smem[2 * 32 * 256 * 4];   // 64 KB: astage dbuf
    float* ast = (float*)smem;

    const int tid = threadIdx.x;
    const int w = tid >> 6;
    const int l31 = tid & 31;
    const int hi = (tid >> 5) & 1;
    const int id = blockIdx.x;
    const int b = id & 7;
    const int n0 = (id >> 3) * 32;

    const float M = norms[b * NA + n0 + l31] * gmaxp[b];
    const float C2 = -M * LOG2E;
    const float L = linv[b * NA + n0 + l31];

    const short* gh = ghi + (size_t)b * NA * KA;
    const short* gl = glo + (size_t)b * NA * KA;
    const short* xp = xb + (size_t)b * CC * NA;
    float* ap = alpha + (size_t)b * NA * NA;

    // persistent B-fragments (block rows n)
    bfrag Bh[2], Bl[2];
#pragma unroll
    for (int kt = 0; kt < 2; kt++) {
        size_t o = (size_t)(n0 + l31) * KA + kt * 16 + hi * 8;
        Bh[kt] = *(const bfrag*)(gh + o);
        Bl[kt] = *(const bfrag*)(gl + o);
    }

    f16v pv0 = {}, pv1 = {};

    for (int it = 0; it < 16; ++it) {
        float* astb = ast + (it & 1) * 8192;

        // ---- fill phase: 2 sub-tiles of 128 m ----
#pragma unroll
        for (int sub = 0; sub < 2; ++sub) {
            const int m0 = it * 256 + sub * 128 + w * 32;
            bfrag Ah[2], Al[2];
#pragma unroll
            for (int kt = 0; kt < 2; kt++) {
                size_t o = (size_t)(m0 + l31) * KA + kt * 16 + hi * 8;
                Ah[kt] = *(const bfrag*)(gh + o);
                Al[kt] = *(const bfrag*)(gl + o);
            }
            f16v sA = {}, sB = {};
            sA = mf(Ah[0], Bh[0], sA); sA = mf(Ah[1], Bh[1], sA);
            sB = mf(Ah[0], Bl[0], sB); sB = mf(Ah[1], Bl[1], sB);
            sB = mf(Al[0], Bh[0], sB); sB = mf(Al[1], Bh[1], sB);

            float a[16];
#pragma unroll
            for (int r = 0; r < 16; r++) a[r] = exp2f(fmaf(sA[r] + sB[r], LOG2E, C2)) * L;

            // stage (swizzled 16B chunks): conflict-free fill
#pragma unroll
            for (int q = 0; q < 4; q++) {
                f4 v = { a[4 * q], a[4 * q + 1], a[4 * q + 2], a[4 * q + 3] };
                int phys = (w * 8 + 2 * q + hi) ^ (l31 & 7);
                *(f4*)&astb[l31 * 256 + sub * 128 + phys * 4] = v;
            }

            // pack P -> bf16 A-fragments (permlane recipe) + PV
            unsigned p0 = pk2(a[0], a[1]),   p1 = pk2(a[2], a[3]);
            unsigned p2 = pk2(a[4], a[5]),   p3 = pk2(a[6], a[7]);
            unsigned p4 = pk2(a[8], a[9]),   p5 = pk2(a[10], a[11]);
            unsigned p6 = pk2(a[12], a[13]), p7 = pk2(a[14], a[15]);
            asm("v_permlane32_swap_b32 %0, %1" : "+v"(p0), "+v"(p2));
            asm("v_permlane32_swap_b32 %0, %1" : "+v"(p1), "+v"(p3));
            asm("v_permlane32_swap_b32 %0, %1" : "+v"(p4), "+v"(p6));
            asm("v_permlane32_swap_b32 %0, %1" : "+v"(p5), "+v"(p7));
            i4 f0 = { (int)p0, (int)p1, (int)p2, (int)p3 };
            i4 f1 = { (int)p4, (int)p5, (int)p6, (int)p7 };
            bfrag pa0 = __builtin_bit_cast(bfrag, f0);
            bfrag pa1 = __builtin_bit_cast(bfrag, f1);

            size_t ox0 = (size_t)l31 * NA + m0 + hi * 8;
            size_t ox1 = (size_t)(32 + l31) * NA + m0 + hi * 8;
            bfrag X00 = *(const bfrag*)(xp + ox0);
            bfrag X01 = *(const bfrag*)(xp + ox0 + 16);
            bfrag X10 = *(const bfrag*)(xp + ox1);
            bfrag X11 = *(const bfrag*)(xp + ox1 + 16);

            pv0 = mf(pa0, X00, pv0); pv0 = mf(pa1, X01, pv0);
            pv1 = mf(pa0, X10, pv1); pv1 = mf(pa1, X11, pv1);
        }

        __syncthreads();   // astb complete; prev iter's LDS store-reads drained

        // ---- store phase: 32 rows x 1 KB contiguous, non-temporal ----
#pragma unroll
        for (int e = 0; e < 8; e++) {
            int flat = e * 256 + tid;
            int row = flat >> 6;          // 0..31
            int c4 = flat & 63;           // f4 chunk within 256 cols
            int grp = c4 >> 5, c32 = c4 & 31;
            int phys = c32 ^ (row & 7);
            f4 v = *(const f4*)&astb[row * 256 + grp * 128 + phys * 4];
            __builtin_nontemporal_store(v, (f4*)(ap + (size_t)(n0 + row) * NA + it * 256 + c4 * 4));
        }
        // no second barrier: next iter fills the other buffer while stores drain
    }
    __syncthreads();

    // ---------------- cross-wave PV reduction (alias smem) ----------------
    float (*pvr0)[CC + 1] = (float(*)[CC + 1])smem;
    float (*pvr1)[CC + 1] = (float(*)[CC + 1])(smem + 32 * (CC + 1) * 4);
    if (w >= 2) {
        float (*buf)[CC + 1] = (w == 2) ? pvr0 : pvr1;
#pragma unroll
        for (int r = 0; r < 16; r++) {
            int nl = (r & 3) + 8 * (r >> 2) + 4 * hi;
            buf[nl][l31]      = pv0[r];
            buf[nl][32 + l31] = pv1[r];
        }
    }
    __syncthreads();
    if (w < 2) {
        float (*buf)[CC + 1] = (w == 0) ? pvr0 : pvr1;
#pragma unroll
        for (int r = 0; r < 16; r++) {
            int nl = (r & 3) + 8 * (r >> 2) + 4 * hi;
            buf[nl][l31]      += pv0[r];
            buf[nl][32 + l31] += pv1[r];
        }
    }
    __syncthreads();

    // ---------------- epilogue: residual + relu ----------------
    const float* xr = x + (size_t)b * CC * NA + n0;
    float* op = out + (size_t)b * CC * NA + n0;
#pragma unroll
    for (int e = 0; e < 8; e++) {
        int idx = e * 256 + tid;
        int c = idx >> 5, n = idx & 31;
        float v = pvr0[n][c] + pvr1[n][c] + xr[(size_t)c * NA + n];
        op[(size_t)c * NA + n] = fmaxf(v, 0.f);
    }
}

extern "C" void kernel_launch(void* const* d_in, const int* in_sizes, int n_in,
                              void* d_out, int out_size, void* d_ws, size_t ws_size,
                              hipStream_t stream) {
    const float* x = (const float*)d_in[0];
    const float* W = (const float*)d_in[1];
    const float* bias = (const float*)d_in[2];

    float* out = (float*)d_out;
    float* alpha = out + (size_t)BB * CC * NA;  // outputs concatenated: out then alpha

    short* ghi = (short*)d_ws;                       // [B][NA][KA] bf16 hi
    short* glo = ghi + (size_t)BB * NA * KA;         // bf16 lo
    short* xb  = glo + (size_t)BB * NA * KA;         // [B][CC][NA] bf16
    float* norms = (float*)(xb + (size_t)BB * CC * NA);
    float* gmaxp = norms + (size_t)BB * NA;
    float* partial = gmaxp + BB;                     // [4][B][NA]
    float* linv = partial + (size_t)4 * BB * NA;     // [B][NA]

    k_g<<<dim3(NA / 256, BB), 256, 0, stream>>>(x, W, bias, ghi, glo, norms);
    k_gmax<<<BB, 256, 0, stream>>>(norms, gmaxp);
    k_xb<<<(BB * CC * NA) / (256 * 4), 256, 0, stream>>>(x, xb);
    k_den<<<4096, 256, 0, stream>>>(ghi, glo, norms, gmaxp, partial);
    k_red<<<BB * NA / 256, 256, 0, stream>>>(partial, linv);
    k_attn2<<<1024, 256, 0, stream>>>(x, ghi, glo, xb, norms, gmaxp, linv, out, alpha);
}